// Round 10
// baseline (165.325 us; speedup 1.0000x reference)
//
#include <hip/hip_runtime.h>
#include <stdint.h>

#define IN_F 4096
#define OUT_F 4096
#define NG 32
#define SPLITK 4
#define NSTEP 16   // (K/SPLITK)/64 k-steps per block

typedef __attribute__((ext_vector_type(8))) _Float16 half8;
typedef __attribute__((ext_vector_type(2))) _Float16 half2t;
typedef __attribute__((ext_vector_type(4))) float floatx4;

__device__ __forceinline__ unsigned pkh(float a, float b) {
  return __builtin_bit_cast(unsigned, __builtin_amdgcn_cvt_pkrtz(a, b));
}

// ---------------------------------------------------------------------------
// Prep (R4-verified): x f32 -> fp16 pair-permuted; scale/zero -> fp16x2 table.
// ---------------------------------------------------------------------------
__global__ __launch_bounds__(256) void prep_kernel(
    const float* __restrict__ x, _Float16* __restrict__ Xh,
    const float* __restrict__ wscale, const int* __restrict__ wzero,
    uint2* __restrict__ SZ, int nxb) {
  int b = blockIdx.x;
  if (b < nxb) {
    int i = b * 256 + threadIdx.x;
    const float4* x4 = (const float4*)x;
    float4 a = x4[2 * i];
    float4 c = x4[2 * i + 1];
    uint4 o;
    o.x = pkh(a.x, c.x);   // (x0,x4)
    o.y = pkh(a.y, c.y);
    o.z = pkh(a.z, c.z);
    o.w = pkh(a.w, c.w);
    ((uint4*)Xh)[i] = o;
  } else {
    int i = (b - nxb) * 256 + threadIdx.x;
    float s = wscale[i];
    int zp = wzero[i];
    _Float16 sh = (_Float16)s;
    _Float16 ch = (_Float16)(float)(1032 + zp);  // exact in fp16
    unsigned s2 = (unsigned)__builtin_bit_cast(unsigned short, sh) * 0x10001u;
    unsigned c2 = (unsigned)__builtin_bit_cast(unsigned short, ch) * 0x10001u;
    SZ[i] = make_uint2(s2, c2);
  }
}

__device__ __forceinline__ uint4 dequant8(unsigned v, uint2 szv) {
  unsigned tx = v ^ 0x88888888u;
  half2t s2 = __builtin_bit_cast(half2t, szv.x);
  half2t c2 = __builtin_bit_cast(half2t, szv.y);
  unsigned p0 = (tx & 0x000F000Fu) | 0x64006400u;          // (n0, n4)
  unsigned p1 = ((tx >> 4) & 0x000F000Fu) | 0x64006400u;   // (n1, n5)
  unsigned p2 = ((tx >> 8) & 0x000F000Fu) | 0x64006400u;   // (n2, n6)
  unsigned p3 = ((tx >> 12) & 0x000F000Fu) | 0x64006400u;  // (n3, n7)
  half2t w0 = (__builtin_bit_cast(half2t, p0) - c2) * s2;
  half2t w1 = (__builtin_bit_cast(half2t, p1) - c2) * s2;
  half2t w2 = (__builtin_bit_cast(half2t, p2) - c2) * s2;
  half2t w3 = (__builtin_bit_cast(half2t, p3) - c2) * s2;
  uint4 o;
  o.x = __builtin_bit_cast(unsigned, w0);
  o.y = __builtin_bit_cast(unsigned, w1);
  o.z = __builtin_bit_cast(unsigned, w2);
  o.w = __builtin_bit_cast(unsigned, w3);
  return o;
}

// ---------------------------------------------------------------------------
// Fused W4A16 GEMM — m97 regime: 4 independent 4-wave blocks per CU.
// 256 threads, 128x128 tile, grid split-K=4 (K=1024/block, 16 steps),
// single-buffered 32 KB LDS, plain 2-barrier loop. Cross-BLOCK wave overlap
// (m114) hides barrier drains — the mechanism R4-R9's single 8-wave block
// could not have. Fused dequant (R4-verified placement: write phase, before
// barrier 2) + XOR chunk swizzle (R4-verified, conflicts = 0).
// Split-K reduction: hardware f32 atomics onto memset-zeroed out.
// ---------------------------------------------------------------------------
__global__ __launch_bounds__(256, 4) void gemm_fused(
    const _Float16* __restrict__ A, const int* __restrict__ wp,
    const uint2* __restrict__ SZ, float* __restrict__ out,
    int M, int N, int K) {
  __shared__ __align__(16) _Float16 Alds[128 * 64];  // 16 KB
  __shared__ __align__(16) _Float16 Blds[128 * 64];  // 16 KB

  const int t = threadIdx.x;
  const int wave = t >> 6, lane = t & 63;
  const int wm = (wave >> 1) * 64, wn = (wave & 1) * 64;
  const int r = lane & 15, quad = lane >> 4, rb = r & 7;
  const int bm = blockIdx.y * 128, bn = blockIdx.x * 128;
  const int kz = blockIdx.z * (K / SPLITK);   // 1024 per z

  floatx4 acc[4][4] = {};

  // Staging decomposition (both A and B): item i = t + 256*j, j=0..3:
  // row = (t>>3) + 32*j, chunk slot = t&7. (row&7) invariant over j.
  const int row = t >> 3, kc = t & 7;
  const int gkc = kc ^ (row & 7);             // swizzled A source chunk

  const _Float16* gA[4];
  const int* gB[4];
  const uint2* gS[4];
  int bofs[4];
#pragma unroll
  for (int j = 0; j < 4; ++j) {
    int rj = row + 32 * j;
    gA[j] = A + (size_t)(bm + rj) * K + kz + gkc * 8;
    gB[j] = wp + (size_t)(bn + rj) * (IN_F / 8) + (kz >> 3) + kc;
    gS[j] = SZ + (size_t)(bn + rj) * NG + (kz >> 7);
    bofs[j] = rj * 64 + ((kc ^ (row & 7)) << 3);   // swizzled B LDS slot
  }

  unsigned v[4];
  uint2 sv[4];
#define LOADV(i)                                                              \
  {                                                                           \
    _Pragma("unroll") for (int j = 0; j < 4; ++j) {                           \
      v[j] = (unsigned)gB[j][(i) * 8];                                        \
      sv[j] = gS[j][(i) >> 1];                                                \
    }                                                                         \
  }

  LOADV(0);
  for (int i = 0; i < NSTEP; ++i) {
    __syncthreads();   // previous MFMA reads done; LDS free for overwrite

    // A: 128x64 fp16, direct-to-LDS (lane-linear dest, pre-swizzled source).
#pragma unroll
    for (int j = 0; j < 4; ++j) {
      const _Float16* src = gA[j] + i * 64;
      __builtin_amdgcn_global_load_lds(
          (const __attribute__((address_space(1))) void*)src,
          (__attribute__((address_space(3))) void*)(&Alds[(t + 256 * j) * 8]),
          16, 0, 0);
    }
    // B: dequant in-register -> swizzled ds_write_b128.
#pragma unroll
    for (int j = 0; j < 4; ++j)
      *(uint4*)&Blds[bofs[j]] = dequant8(v[j], sv[j]);
    if (i + 1 < NSTEP) LOADV(i + 1);   // next step's packed B rides the MFMAs

    __syncthreads();   // drains vmcnt (A DMA) + lgkm (B writes): tile visible

#pragma unroll
    for (int ks = 0; ks < 2; ++ks) {
      half8 af[4], bf[4];
#pragma unroll
      for (int mi = 0; mi < 4; ++mi) {
        int R = wm + mi * 16 + r;      // R&7 == rb
        af[mi] = *(const half8*)&Alds[R * 64 + (((ks * 4 + quad) ^ rb) << 3)];
      }
#pragma unroll
      for (int ni = 0; ni < 4; ++ni) {
        int R = wn + ni * 16 + r;
        bf[ni] = *(const half8*)&Blds[R * 64 + (((ks * 4 + quad) ^ rb) << 3)];
      }
#pragma unroll
      for (int mi = 0; mi < 4; ++mi)
#pragma unroll
        for (int ni = 0; ni < 4; ++ni)
          acc[mi][ni] = __builtin_amdgcn_mfma_f32_16x16x32_f16(
              af[mi], bf[ni], acc[mi][ni], 0, 0, 0);
    }
  }

  // Split-K reduction: one hw f32 atomic per output element (out pre-zeroed).
  // C/D layout: col = lane&15, row = quad*4 + reg.
#pragma unroll
  for (int mi = 0; mi < 4; ++mi) {
#pragma unroll
    for (int ni = 0; ni < 4; ++ni) {
#pragma unroll
      for (int i2 = 0; i2 < 4; ++i2) {
        int grow = bm + wm + mi * 16 + quad * 4 + i2;
        int gcol = bn + wn + ni * 16 + r;
        unsafeAtomicAdd(&out[(size_t)grow * N + gcol], acc[mi][ni][i2]);
      }
    }
  }
}

extern "C" void kernel_launch(void* const* d_in, const int* in_sizes, int n_in,
                              void* d_out, int out_size, void* d_ws, size_t ws_size,
                              hipStream_t stream) {
  const float* x = (const float*)d_in[0];
  const int* wp = (const int*)d_in[1];
  const float* wscale = (const float*)d_in[2];
  const int* wzero = (const int*)d_in[3];
  float* out = (float*)d_out;

  int M = in_sizes[0] / IN_F;  // 1024

  // Workspace: Xh (fp16 M*K = 8.39 MB) | SZ (1 MB)
  _Float16* Xh = (_Float16*)d_ws;
  uint2* SZ = (uint2*)((char*)d_ws + (size_t)M * IN_F * 2);

  hipMemsetAsync(out, 0, (size_t)M * OUT_F * sizeof(float), stream);

  int nxb = (M * IN_F / 8) / 256;       // 2048 blocks for x-convert
  int nzb = (OUT_F * NG) / 256;         // 512 blocks for scale/zero table
  prep_kernel<<<nxb + nzb, 256, 0, stream>>>(x, Xh, wscale, wzero, SZ, nxb);

  dim3 grid(OUT_F / 128, M / 128, SPLITK);  // (32, 8, 4) = 1024 blocks = 4/CU
  gemm_fused<<<grid, 256, 0, stream>>>(Xh, wp, SZ, out, M, OUT_F, IN_F);
}

// Round 11
// 137.107 us; speedup vs baseline: 1.2058x; 1.2058x over previous
//
#include <hip/hip_runtime.h>
#include <stdint.h>

#define IN_F 4096
#define OUT_F 4096
#define NG 32
#define NSTEP 32   // 2048 k per in-block half / BK=64

typedef __attribute__((ext_vector_type(8))) _Float16 half8;
typedef __attribute__((ext_vector_type(2))) _Float16 half2t;
typedef __attribute__((ext_vector_type(4))) float floatx4;

__device__ __forceinline__ unsigned pkh(float a, float b) {
  return __builtin_bit_cast(unsigned, __builtin_amdgcn_cvt_pkrtz(a, b));
}

// ---------------------------------------------------------------------------
// Prep (R4-verified): x f32 -> fp16 pair-permuted; scale/zero -> fp16x2 table.
// ---------------------------------------------------------------------------
__global__ __launch_bounds__(256) void prep_kernel(
    const float* __restrict__ x, _Float16* __restrict__ Xh,
    const float* __restrict__ wscale, const int* __restrict__ wzero,
    uint2* __restrict__ SZ, int nxb) {
  int b = blockIdx.x;
  if (b < nxb) {
    int i = b * 256 + threadIdx.x;
    const float4* x4 = (const float4*)x;
    float4 a = x4[2 * i];
    float4 c = x4[2 * i + 1];
    uint4 o;
    o.x = pkh(a.x, c.x);   // (x0,x4)
    o.y = pkh(a.y, c.y);
    o.z = pkh(a.z, c.z);
    o.w = pkh(a.w, c.w);
    ((uint4*)Xh)[i] = o;
  } else {
    int i = (b - nxb) * 256 + threadIdx.x;
    float s = wscale[i];
    int zp = wzero[i];
    _Float16 sh = (_Float16)s;
    _Float16 ch = (_Float16)(float)(1032 + zp);  // exact in fp16
    unsigned s2 = (unsigned)__builtin_bit_cast(unsigned short, sh) * 0x10001u;
    unsigned c2 = (unsigned)__builtin_bit_cast(unsigned short, ch) * 0x10001u;
    SZ[i] = make_uint2(s2, c2);
  }
}

__device__ __forceinline__ uint4 dequant8(unsigned v, uint2 szv) {
  unsigned tx = v ^ 0x88888888u;
  half2t s2 = __builtin_bit_cast(half2t, szv.x);
  half2t c2 = __builtin_bit_cast(half2t, szv.y);
  unsigned p0 = (tx & 0x000F000Fu) | 0x64006400u;          // (n0, n4)
  unsigned p1 = ((tx >> 4) & 0x000F000Fu) | 0x64006400u;   // (n1, n5)
  unsigned p2 = ((tx >> 8) & 0x000F000Fu) | 0x64006400u;   // (n2, n6)
  unsigned p3 = ((tx >> 12) & 0x000F000Fu) | 0x64006400u;  // (n3, n7)
  half2t w0 = (__builtin_bit_cast(half2t, p0) - c2) * s2;
  half2t w1 = (__builtin_bit_cast(half2t, p1) - c2) * s2;
  half2t w2 = (__builtin_bit_cast(half2t, p2) - c2) * s2;
  half2t w3 = (__builtin_bit_cast(half2t, p3) - c2) * s2;
  uint4 o;
  o.x = __builtin_bit_cast(unsigned, w0);
  o.y = __builtin_bit_cast(unsigned, w1);
  o.z = __builtin_bit_cast(unsigned, w2);
  o.w = __builtin_bit_cast(unsigned, w3);
  return o;
}

// ---------------------------------------------------------------------------
// Fused W4A16 GEMM — 2 independent 4-wave barrier scopes per CU.
// Block: 64(M) x 128(N), 256 thr = 4 waves: (k-half h = wave>>1) x (n-half).
// Each wave: full 64x64 subtile, acc[4][4], 32 MFMA/step (R4 density).
// In-block split-K: half h covers k in [h*2048, h*2048+2048), 32 steps BK=64.
// Grid (32,16) = 512 blocks = 2 blocks/CU (LDS 48 KB) -> cross-BLOCK overlap
// (m114/m97 mechanism) hides each block's barrier drains.
// Stage window minimized: dequant runs in the PREVIOUS compute phase (wreg
// loaded 2 steps ahead, named wA/wB sets, unroll-by-2); window = 4 DMA + 8
// ds_write_b128 only. XOR chunk swizzle as in R4 (conflicts = 0).
// Epilogue: in-LDS k-half reduction, plain f32 stores (no split-K traffic).
// ---------------------------------------------------------------------------
__global__ __launch_bounds__(256, 2) void gemm_fused(
    const _Float16* __restrict__ A, const int* __restrict__ wp,
    const uint2* __restrict__ SZ, float* __restrict__ out,
    int M, int N, int K) {
  __shared__ __align__(16) _Float16 Alds[2 * 64 * 64];    // [h][64x64]  16 KB
  __shared__ __align__(16) _Float16 Blds[2 * 128 * 64];   // [h][128x64] 32 KB

  const int t = threadIdx.x;
  const int wave = t >> 6, lane = t & 63;
  const int h = wave >> 1;            // k-half this wave computes
  const int wn = (wave & 1) * 64;     // n-offset
  const int r = lane & 15, quad = lane >> 4, rb = r & 7;
  const int bm = blockIdx.y * 64, bn = blockIdx.x * 128;

  floatx4 acc[4][4] = {};

  const int kc = t & 7;               // 16B chunk slot
  const int row8 = t >> 3;            // 0..31
  const int gkc = kc ^ (row8 & 7);    // swizzled source chunk (A)

  // ---- A staging: j=0..3: half=j>>1, row = row8 + 32*(j&1) (0..63) ----
  const _Float16* gA[4];
#pragma unroll
  for (int j = 0; j < 4; ++j) {
    int half = j >> 1, arow = row8 + 32 * (j & 1);
    gA[j] = A + (size_t)(bm + arow) * K + half * 2048 + gkc * 8;
  }

#define STAGE_A(i)                                                            \
  {                                                                           \
    _Pragma("unroll") for (int j = 0; j < 4; ++j) {                           \
      const _Float16* src = gA[j] + (i) * 64;                                 \
      int dst = (j >> 1) * 4096 + (t + 256 * (j & 1)) * 8;                    \
      __builtin_amdgcn_global_load_lds(                                       \
          (const __attribute__((address_space(1))) void*)src,                 \
          (__attribute__((address_space(3))) void*)(&Alds[dst]), 16, 0, 0);   \
    }                                                                         \
  }

  // ---- B staging: j=0..7: half=j>>2, row = row8 + 32*(j&3) (0..127) ----
  const int* gB[8];
  const uint2* gS[8];
  int bofs[8];
#pragma unroll
  for (int j = 0; j < 8; ++j) {
    int half = j >> 2, brow = row8 + 32 * (j & 3);
    gB[j] = wp + (size_t)(bn + brow) * (IN_F / 8) + half * 256 + kc;
    gS[j] = SZ + (size_t)(bn + brow) * NG + half * 16;
    bofs[j] = half * 8192 + brow * 64 + ((kc ^ (row8 & 7)) << 3);
  }

#define LOADV(i, w, s)                                                        \
  {                                                                           \
    _Pragma("unroll") for (int j = 0; j < 8; ++j) {                           \
      w[j] = (unsigned)gB[j][(i) * 8];                                        \
      s[j] = gS[j][(i) >> 1];                                                 \
    }                                                                         \
  }

#define DEQ(w, s)                                                             \
  {                                                                           \
    _Pragma("unroll") for (int j = 0; j < 8; ++j) dreg[j] = dequant8(w[j], s[j]); \
  }

#define WRITE_B()                                                             \
  {                                                                           \
    _Pragma("unroll") for (int j = 0; j < 8; ++j)                             \
      *(uint4*)&Blds[bofs[j]] = dreg[j];                                      \
  }

#define COMPUTE()                                                             \
  {                                                                           \
    const _Float16* Ab = &Alds[h * 4096];                                     \
    const _Float16* Bb = &Blds[h * 8192];                                     \
    _Pragma("unroll") for (int ks = 0; ks < 2; ++ks) {                        \
      half8 af[4], bf[4];                                                     \
      _Pragma("unroll") for (int mi = 0; mi < 4; ++mi) {                      \
        int R = mi * 16 + r;                                                  \
        af[mi] = *(const half8*)&Ab[R * 64 + (((ks * 4 + quad) ^ rb) << 3)];  \
      }                                                                       \
      _Pragma("unroll") for (int ni = 0; ni < 4; ++ni) {                      \
        int R = wn + ni * 16 + r;                                             \
        bf[ni] = *(const half8*)&Bb[R * 64 + (((ks * 4 + quad) ^ rb) << 3)];  \
      }                                                                       \
      _Pragma("unroll") for (int mi = 0; mi < 4; ++mi)                        \
        _Pragma("unroll") for (int ni = 0; ni < 4; ++ni)                      \
          acc[mi][ni] = __builtin_amdgcn_mfma_f32_16x16x32_f16(               \
              af[mi], bf[ni], acc[mi][ni], 0, 0, 0);                          \
    }                                                                         \
  }

  unsigned wA[8], wB[8];
  uint2 sA[8], sB[8];
  uint4 dreg[8];

  // ---- prologue: dreg = B(0); wB = raw B(1) ----
  LOADV(0, wA, sA);
  DEQ(wA, sA);
  LOADV(1, wB, sB);

  for (int i = 0; i < NSTEP; i += 2) {
    // ---- step i (dreg holds B(i)) ----
    __syncthreads();                  // prev compute done; LDS free
    STAGE_A(i);
    WRITE_B();
    __syncthreads();                  // vmcnt+lgkm drained: tile visible
    if (i + 2 < NSTEP) LOADV(i + 2, wA, sA);  // rides under MFMAs
    COMPUTE();
    DEQ(wB, sB);                      // dreg = B(i+1); wB loaded a step ago
    // ---- step i+1 ----
    __syncthreads();
    STAGE_A(i + 1);
    WRITE_B();
    __syncthreads();
    if (i + 3 < NSTEP) LOADV(i + 3, wB, sB);
    COMPUTE();
    if (i + 2 < NSTEP) DEQ(wA, sA);   // dreg = B(i+2)
  }

  // ---- in-block k-half reduction via LDS (32 KB in Blds), plain stores ----
  floatx4* red = (floatx4*)Blds;
  __syncthreads();                    // all waves done reading Blds
  if (h == 1) {
#pragma unroll
    for (int mi = 0; mi < 4; ++mi)
#pragma unroll
      for (int ni = 0; ni < 4; ++ni)
        red[((wave & 1) * 16 + mi * 4 + ni) * 64 + lane] = acc[mi][ni];
  }
  __syncthreads();
  if (h == 0) {
#pragma unroll
    for (int mi = 0; mi < 4; ++mi) {
#pragma unroll
      for (int ni = 0; ni < 4; ++ni) {
        acc[mi][ni] += red[((wave & 1) * 16 + mi * 4 + ni) * 64 + lane];
#pragma unroll
        for (int i2 = 0; i2 < 4; ++i2) {
          int grow = bm + mi * 16 + quad * 4 + i2;
          int gcol = bn + wn + ni * 16 + r;
          out[(size_t)grow * N + gcol] = acc[mi][ni][i2];
        }
      }
    }
  }
}

extern "C" void kernel_launch(void* const* d_in, const int* in_sizes, int n_in,
                              void* d_out, int out_size, void* d_ws, size_t ws_size,
                              hipStream_t stream) {
  const float* x = (const float*)d_in[0];
  const int* wp = (const int*)d_in[1];
  const float* wscale = (const float*)d_in[2];
  const int* wzero = (const int*)d_in[3];
  float* out = (float*)d_out;

  int M = in_sizes[0] / IN_F;  // 1024

  // Workspace: Xh (fp16 M*K = 8.39 MB) | SZ (1 MB)
  _Float16* Xh = (_Float16*)d_ws;
  uint2* SZ = (uint2*)((char*)d_ws + (size_t)M * IN_F * 2);

  int nxb = (M * IN_F / 8) / 256;       // 2048 blocks for x-convert
  int nzb = (OUT_F * NG) / 256;         // 512 blocks for scale/zero table
  prep_kernel<<<nxb + nzb, 256, 0, stream>>>(x, Xh, wscale, wzero, SZ, nxb);

  // (32, 16) = 512 blocks = 2/CU. Blocks sharing bn land on one XCD
  // (32 n-tiles % 8 == 0) -> B-slices L2-resident; A (8.4 MB) LLC-resident.
  dim3 grid(OUT_F / 128, M / 64);
  gemm_fused<<<grid, 256, 0, stream>>>(Xh, wp, SZ, out, M, OUT_F, IN_F);
}